// Round 7
// baseline (777.198 us; speedup 1.0000x reference)
//
#include <hip/hip_runtime.h>
#include <math.h>

#define BN_EPS 1e-5f

typedef float floatx4 __attribute__((ext_vector_type(4)));
typedef short shortx4 __attribute__((ext_vector_type(4)));
typedef short shortx8 __attribute__((ext_vector_type(8)));
typedef __bf16 bf16x8 __attribute__((ext_vector_type(8)));

// ---- bf16 helpers (RNE, branch-free; no NaNs in this workload) ----
__device__ __forceinline__ unsigned short f2b(float f) {
    unsigned int u = __builtin_bit_cast(unsigned int, f);
    u += 0x7fffu + ((u >> 16) & 1u);
    return (unsigned short)(u >> 16);
}
__device__ __forceinline__ float b2f(unsigned short s) {
    unsigned int u = ((unsigned int)s) << 16;
    return __builtin_bit_cast(float, u);
}
__device__ __forceinline__ float b2f_s(short s) { return b2f((unsigned short)s); }

// ---------- edge-index layout detection (int32 vs int64 storage) ----------
__global__ __launch_bounds__(256)
void k_detect(const unsigned int* __restrict__ ei, int n_check, int* __restrict__ flag) {
    __shared__ int any;
    if (threadIdx.x == 0) any = 0;
    __syncthreads();
    for (int i = threadIdx.x; i < n_check; i += 256) {
        if (ei[2 * i + 1] != 0u) any = 1;
    }
    __syncthreads();
    if (threadIdx.x == 0) *flag = any;   // 1 => int32 layout, 0 => int64 layout
}

// ---------- convert + degree count fused ----------
__global__ __launch_bounds__(256)
void k_convert(const void* __restrict__ ei_raw, const int* __restrict__ flag,
               int* __restrict__ src, int* __restrict__ dst, int* __restrict__ cnt, int E) {
    int e = blockIdx.x * 256 + threadIdx.x;
    if (e >= E) return;
    int s, d;
    if (*flag) {
        const int* a = (const int*)ei_raw;
        s = a[e]; d = a[E + e];
    } else {
        const long long* a = (const long long*)ei_raw;
        s = (int)a[e]; d = (int)a[E + e];
    }
    src[e] = s;
    dst[e] = d;
    atomicAdd(&cnt[d], 1);
}

// ---------- 3-phase parallel exclusive scan ----------
__global__ __launch_bounds__(1024)
void k_scan_sum(const int* __restrict__ cnt, int* __restrict__ bsum, int N) {
    __shared__ int s[1024];
    int i = blockIdx.x * 1024 + threadIdx.x;
    s[threadIdx.x] = (i < N) ? cnt[i] : 0;
    __syncthreads();
    for (int off = 512; off > 0; off >>= 1) {
        if (threadIdx.x < off) s[threadIdx.x] += s[threadIdx.x + off];
        __syncthreads();
    }
    if (threadIdx.x == 0) bsum[blockIdx.x] = s[0];
}

__global__ __launch_bounds__(1024)
void k_scan_part(int* __restrict__ bsum, int nb) {
    __shared__ int s[1024];
    int t = threadIdx.x;
    int v = (t < nb) ? bsum[t] : 0;
    s[t] = v;
    __syncthreads();
    for (int off = 1; off < 1024; off <<= 1) {
        int tmp = (t >= off) ? s[t - off] : 0;
        __syncthreads();
        s[t] += tmp;
        __syncthreads();
    }
    if (t < nb) bsum[t] = s[t] - v;     // exclusive
}

__global__ __launch_bounds__(1024)
void k_scan_final(const int* __restrict__ cnt, const int* __restrict__ bsum,
                  int* __restrict__ row_ptr, int* __restrict__ cursor,
                  float* __restrict__ dinv, int N) {
    __shared__ int s[1024];
    int b = blockIdx.x, t = threadIdx.x;
    int i = b * 1024 + t;
    int v = (i < N) ? cnt[i] : 0;
    s[t] = v;
    __syncthreads();
    for (int off = 1; off < 1024; off <<= 1) {
        int tmp = (t >= off) ? s[t - off] : 0;
        __syncthreads();
        s[t] += tmp;
        __syncthreads();
    }
    if (i < N) {
        int excl = bsum[b] + s[t] - v;
        row_ptr[i] = excl;
        cursor[i]  = excl;
        dinv[i] = rsqrtf((float)(v + 1));
        if (i == N - 1) row_ptr[N] = excl + v;
    }
}

// ---------- CSR fill: packed (src, weight) pairs ----------
__global__ __launch_bounds__(256)
void k_fill(const int* __restrict__ src, const int* __restrict__ dst,
            int* __restrict__ cursor, const float* __restrict__ dinv,
            int2* __restrict__ csr_sw, int E) {
    int e = blockIdx.x * 256 + threadIdx.x;
    if (e >= E) return;
    int s = src[e], d = dst[e];
    int p = atomicAdd(&cursor[d], 1);
    float w = dinv[s] * dinv[d];
    csr_sw[p] = make_int2(s, __builtin_bit_cast(int, w));
}

// ---------- fused BN1 stats + raw bf16 cast of x (x read ONCE) ----------
// Flat grid-stride over float4 quads, exact bulk region with unconditional
// 4-deep unroll. NT loads: x is dead after this kernel.
__global__ __launch_bounds__(256)
void k_bnstats_cast(const float* __restrict__ x, unsigned short* __restrict__ xb,
                    float* __restrict__ sum8, float* __restrict__ sumsq8,
                    int NQ, int F) {
    __shared__ float ls[512], lq[512];
    int t   = threadIdx.x;
    int tid = blockIdx.x * 256 + t;
    int G   = gridDim.x * 256;           // multiple of F/4
    int cq  = tid & ((F >> 2) - 1);      // column quad, invariant over the stride
    const floatx4* xv = (const floatx4*)x;
    shortx4* xo = (shortx4*)xb;

    float s0 = 0.f, s1 = 0.f, s2 = 0.f, s3 = 0.f;
    float q0 = 0.f, q1 = 0.f, q2 = 0.f, q3 = 0.f;

    int G4 = G << 2;
    int Qfull = NQ - (NQ % G4);
    int i = tid;
    for (; i < Qfull; i += G4) {
        floatx4 a = __builtin_nontemporal_load(&xv[i]);
        floatx4 b = __builtin_nontemporal_load(&xv[i + G]);
        floatx4 c = __builtin_nontemporal_load(&xv[i + 2 * G]);
        floatx4 d = __builtin_nontemporal_load(&xv[i + 3 * G]);
        shortx4 o;
        o[0] = (short)f2b(a[0]); o[1] = (short)f2b(a[1]);
        o[2] = (short)f2b(a[2]); o[3] = (short)f2b(a[3]);
        xo[i] = o;
        s0 += a[0]; s1 += a[1]; s2 += a[2]; s3 += a[3];
        q0 += a[0] * a[0]; q1 += a[1] * a[1]; q2 += a[2] * a[2]; q3 += a[3] * a[3];
        o[0] = (short)f2b(b[0]); o[1] = (short)f2b(b[1]);
        o[2] = (short)f2b(b[2]); o[3] = (short)f2b(b[3]);
        xo[i + G] = o;
        s0 += b[0]; s1 += b[1]; s2 += b[2]; s3 += b[3];
        q0 += b[0] * b[0]; q1 += b[1] * b[1]; q2 += b[2] * b[2]; q3 += b[3] * b[3];
        o[0] = (short)f2b(c[0]); o[1] = (short)f2b(c[1]);
        o[2] = (short)f2b(c[2]); o[3] = (short)f2b(c[3]);
        xo[i + 2 * G] = o;
        s0 += c[0]; s1 += c[1]; s2 += c[2]; s3 += c[3];
        q0 += c[0] * c[0]; q1 += c[1] * c[1]; q2 += c[2] * c[2]; q3 += c[3] * c[3];
        o[0] = (short)f2b(d[0]); o[1] = (short)f2b(d[1]);
        o[2] = (short)f2b(d[2]); o[3] = (short)f2b(d[3]);
        xo[i + 3 * G] = o;
        s0 += d[0]; s1 += d[1]; s2 += d[2]; s3 += d[3];
        q0 += d[0] * d[0]; q1 += d[1] * d[1]; q2 += d[2] * d[2]; q3 += d[3] * d[3];
    }
    for (; i < NQ; i += G) {
        floatx4 a = __builtin_nontemporal_load(&xv[i]);
        shortx4 o;
        o[0] = (short)f2b(a[0]); o[1] = (short)f2b(a[1]);
        o[2] = (short)f2b(a[2]); o[3] = (short)f2b(a[3]);
        xo[i] = o;
        s0 += a[0]; s1 += a[1]; s2 += a[2]; s3 += a[3];
        q0 += a[0] * a[0]; q1 += a[1] * a[1]; q2 += a[2] * a[2]; q3 += a[3] * a[3];
    }

    for (int c = t; c < F; c += 256) { ls[c] = 0.f; lq[c] = 0.f; }
    __syncthreads();
    atomicAdd(&ls[cq * 4 + 0], s0); atomicAdd(&ls[cq * 4 + 1], s1);
    atomicAdd(&ls[cq * 4 + 2], s2); atomicAdd(&ls[cq * 4 + 3], s3);
    atomicAdd(&lq[cq * 4 + 0], q0); atomicAdd(&lq[cq * 4 + 1], q1);
    atomicAdd(&lq[cq * 4 + 2], q2); atomicAdd(&lq[cq * 4 + 3], q3);
    __syncthreads();
    int rep = (blockIdx.x & 7) * F;
    for (int c = t; c < F; c += 256) {
        atomicAdd(&sum8[rep + c],   ls[c]);
        atomicAdd(&sumsq8[rep + c], lq[c]);
    }
}

// ---------- finalize BN affine from nrep replicated partials ----------
__global__ __launch_bounds__(256)
void k_bnfin(const float* __restrict__ sum, const float* __restrict__ sumsq,
             const float* __restrict__ gamma, const float* __restrict__ beta,
             float* __restrict__ a, float* __restrict__ b, int N, int F, int nrep) {
    int c = blockIdx.x * 256 + threadIdx.x;
    if (c >= F) return;
    float s = 0.f, ss = 0.f;
    for (int i = 0; i < nrep; ++i) { s += sum[i * F + c]; ss += sumsq[i * F + c]; }
    float m   = s / (float)N;
    float var = ss / (float)N - m * m;
    float rs  = rsqrtf(var + BN_EPS);
    float aa  = gamma[c] * rs;
    a[c] = aa;
    b[c] = beta[c] - m * aa;
}

// ---------- cast + transpose all 4 weights; W1 scaled by BN1 a[k] ----------
__global__ __launch_bounds__(256)
void k_castWT4(const float* __restrict__ W1, const float* __restrict__ W2,
               const float* __restrict__ W3, const float* __restrict__ W4,
               unsigned short* __restrict__ T1, unsigned short* __restrict__ T2,
               unsigned short* __restrict__ T3, unsigned short* __restrict__ T4,
               const float* __restrict__ bna, int F, int H) {
    int i = blockIdx.x * 256 + threadIdx.x;
    int n1 = F * H, n2 = H * H;
    if (i < n1) {
        int n = i / F, k = i % F;
        T1[i] = f2b(W1[(size_t)k * H + n] * bna[k]);
        return;
    }
    const float* W; unsigned short* T; int j;
    if (i < n1 + n2)          { W = W2; T = T2; j = i - n1; }
    else if (i < n1 + 2 * n2) { W = W3; T = T3; j = i - n1 - n2; }
    else if (i < n1 + 3 * n2) { W = W4; T = T4; j = i - n1 - 2 * n2; }
    else return;
    int n = j / H, k = j % H;
    T[j] = f2b(W[(size_t)k * H + n]);
}

// ---------- cvec: c_j = sum_k bnb[k] * W1[k,j]  (BN1 shift folded through GEMM1) ----------
__global__ __launch_bounds__(256)
void k_cvec(const float* __restrict__ W1, const float* __restrict__ bnb,
            float* __restrict__ cvec, int F, int H) {
    int j = threadIdx.x;           // H == 256 == blockDim
    int kslice = F / 8;
    int k0 = blockIdx.x * kslice;
    float s = 0.f;
    for (int k = k0; k < k0 + kslice; ++k)
        s += bnb[k] * W1[(size_t)k * H + j];
    atomicAdd(&cvec[j], s);
}

// ---------- bf16 MFMA GEMM: C[M,NC] = A[M,K] @ Wt[NC,K]^T ----------
__device__ __forceinline__ void glds16(const void* g, void* l) {
    __builtin_amdgcn_global_load_lds(
        (const __attribute__((address_space(1))) unsigned int*)g,
        (__attribute__((address_space(3))) unsigned int*)l, 16, 0, 0);
}

__global__ __launch_bounds__(256)
void k_gemm_bf16(const unsigned short* __restrict__ A, const unsigned short* __restrict__ Bt,
                 unsigned short* __restrict__ C, int K, int NC) {
    __shared__ unsigned short As[128 * 32];
    __shared__ unsigned short Bs[128 * 32];
    int tid  = threadIdx.x;
    int wave = tid >> 6, lane = tid & 63;
    int row0 = blockIdx.x * 128;
    int col0 = blockIdx.y * 128;
    int wr = (wave & 1) * 64;
    int wc = (wave >> 1) * 64;

    floatx4 acc[4][4];
    #pragma unroll
    for (int i = 0; i < 4; i++)
        #pragma unroll
        for (int j = 0; j < 4; j++) acc[i][j] = (floatx4){0.f, 0.f, 0.f, 0.f};

    int cA = tid * 16;
    int cB = cA + 4096;
    const char* Ab = (const char*)A;
    const char* Bb = (const char*)Bt;
    size_t a_off0 = (size_t)(row0 + (cA >> 6)) * K * 2 + (cA & 63);
    size_t a_off1 = (size_t)(row0 + (cB >> 6)) * K * 2 + (cB & 63);
    size_t b_off0 = (size_t)(col0 + (cA >> 6)) * K * 2 + (cA & 63);
    size_t b_off1 = (size_t)(col0 + (cB >> 6)) * K * 2 + (cB & 63);

    int lm  = lane & 15;
    int lk8 = (lane >> 4) * 8;

    for (int ks = 0; ks < K; ks += 32) {
        size_t koff = (size_t)ks * 2;
        glds16(Ab + a_off0 + koff, (char*)As + cA);
        glds16(Ab + a_off1 + koff, (char*)As + cA + 4096);
        glds16(Bb + b_off0 + koff, (char*)Bs + cA);
        glds16(Bb + b_off1 + koff, (char*)Bs + cA + 4096);
        __syncthreads();

        bf16x8 af[4], bfr[4];
        #pragma unroll
        for (int i = 0; i < 4; i++) {
            shortx8 s = *(const shortx8*)&As[(wr + i * 16 + lm) * 32 + lk8];
            af[i] = __builtin_bit_cast(bf16x8, s);
        }
        #pragma unroll
        for (int j = 0; j < 4; j++) {
            shortx8 s = *(const shortx8*)&Bs[(wc + j * 16 + lm) * 32 + lk8];
            bfr[j] = __builtin_bit_cast(bf16x8, s);
        }
        #pragma unroll
        for (int i = 0; i < 4; i++)
            #pragma unroll
            for (int j = 0; j < 4; j++)
                acc[i][j] = __builtin_amdgcn_mfma_f32_16x16x32_bf16(af[i], bfr[j], acc[i][j], 0, 0, 0);
        __syncthreads();
    }

    int crow = row0 + wr + (lane >> 4) * 4;
    int ccol = col0 + wc + lm;
    #pragma unroll
    for (int i = 0; i < 4; i++)
        #pragma unroll
        for (int j = 0; j < 4; j++)
            #pragma unroll
            for (int r = 0; r < 4; r++)
                C[(size_t)(crow + i * 16 + r) * NC + ccol + j * 16] = f2b(acc[i][j][r]);
}

// ---------- CSR gather-aggregation (row-major, proven-best structure) ----------
// Wave per node, half-wave owns 8 contiguous edges per iteration. Plain cached
// loads/stores (CSR reused 4x; hout feeds next GEMM). Optional fused BN column
// stats (layer 4): exact f32 pre-rounding values accumulated via LDS + 64-replica
// global atomics, removing the separate bnstats pass over 25.6 MB.
__global__ __launch_bounds__(256)
void k_agg(const unsigned short* __restrict__ hin, unsigned short* __restrict__ hout,
           const int* __restrict__ row_ptr, const int2* __restrict__ csr_sw,
           const float* __restrict__ dinv, const float* __restrict__ bias,
           const float* __restrict__ cvec, int N,
           float* __restrict__ colsum, float* __restrict__ colsq) {
    const int H = 256;
    __shared__ float ls[256], lq[256];
    int t = threadIdx.x;
    bool stats = colsum != nullptr;      // uniform across block
    if (stats) {
        ls[t] = 0.f; lq[t] = 0.f;
        __syncthreads();
    }
    int node = blockIdx.x * 4 + (t >> 6);
    bool active = node < N;
    int nodec = active ? node : 0;
    int lane = t & 63;
    int half = lane >> 5;
    int f = (lane & 31) * 8;
    float acc[8];
    float ws;
    float di = dinv[nodec];
    if (half == 0) {
        shortx8 hv = *(const shortx8*)&hin[(size_t)nodec * H + f];
        float sl = di * di;
        ws = sl;
        #pragma unroll
        for (int j = 0; j < 8; ++j) acc[j] = b2f_s(hv[j]) * sl;
    } else {
        ws = 0.f;
        #pragma unroll
        for (int j = 0; j < 8; ++j) acc[j] = 0.f;
    }
    int e0 = active ? row_ptr[nodec] : 0;
    int e1 = active ? row_ptr[nodec + 1] : 0;
    const long long* cs = (const long long*)csr_sw;
    int e = e0;
    // bulk: 16 edges per iteration, half-wave takes 8 contiguous
    for (; e + 16 <= e1; e += 16) {
        int base = e + half * 8;
        long long p0 = cs[base + 0];
        long long p1 = cs[base + 1];
        long long p2 = cs[base + 2];
        long long p3 = cs[base + 3];
        long long p4 = cs[base + 4];
        long long p5 = cs[base + 5];
        long long p6 = cs[base + 6];
        long long p7 = cs[base + 7];
        shortx8 r0 = *(const shortx8*)&hin[(size_t)(int)p0 * H + f];
        shortx8 r1 = *(const shortx8*)&hin[(size_t)(int)p1 * H + f];
        shortx8 r2 = *(const shortx8*)&hin[(size_t)(int)p2 * H + f];
        shortx8 r3 = *(const shortx8*)&hin[(size_t)(int)p3 * H + f];
        shortx8 r4 = *(const shortx8*)&hin[(size_t)(int)p4 * H + f];
        shortx8 r5 = *(const shortx8*)&hin[(size_t)(int)p5 * H + f];
        shortx8 r6 = *(const shortx8*)&hin[(size_t)(int)p6 * H + f];
        shortx8 r7 = *(const shortx8*)&hin[(size_t)(int)p7 * H + f];
        float w0 = __builtin_bit_cast(float, (int)(p0 >> 32));
        float w1 = __builtin_bit_cast(float, (int)(p1 >> 32));
        float w2 = __builtin_bit_cast(float, (int)(p2 >> 32));
        float w3 = __builtin_bit_cast(float, (int)(p3 >> 32));
        float w4 = __builtin_bit_cast(float, (int)(p4 >> 32));
        float w5 = __builtin_bit_cast(float, (int)(p5 >> 32));
        float w6 = __builtin_bit_cast(float, (int)(p6 >> 32));
        float w7 = __builtin_bit_cast(float, (int)(p7 >> 32));
        ws += ((w0 + w1) + (w2 + w3)) + ((w4 + w5) + (w6 + w7));
        #pragma unroll
        for (int j = 0; j < 8; ++j) {
            float t0 = w0 * b2f_s(r0[j]) + w1 * b2f_s(r1[j])
                     + w2 * b2f_s(r2[j]) + w3 * b2f_s(r3[j]);
            float t1 = w4 * b2f_s(r4[j]) + w5 * b2f_s(r5[j])
                     + w6 * b2f_s(r6[j]) + w7 * b2f_s(r7[j]);
            acc[j] += t0 + t1;
        }
    }
    // mid: one optional 8-edge step, half-wave takes 4 contiguous
    if (e + 8 <= e1) {
        int base = e + half * 4;
        long long p0 = cs[base + 0];
        long long p1 = cs[base + 1];
        long long p2 = cs[base + 2];
        long long p3 = cs[base + 3];
        shortx8 r0 = *(const shortx8*)&hin[(size_t)(int)p0 * H + f];
        shortx8 r1 = *(const shortx8*)&hin[(size_t)(int)p1 * H + f];
        shortx8 r2 = *(const shortx8*)&hin[(size_t)(int)p2 * H + f];
        shortx8 r3 = *(const shortx8*)&hin[(size_t)(int)p3 * H + f];
        float w0 = __builtin_bit_cast(float, (int)(p0 >> 32));
        float w1 = __builtin_bit_cast(float, (int)(p1 >> 32));
        float w2 = __builtin_bit_cast(float, (int)(p2 >> 32));
        float w3 = __builtin_bit_cast(float, (int)(p3 >> 32));
        ws += (w0 + w1) + (w2 + w3);
        #pragma unroll
        for (int j = 0; j < 8; ++j)
            acc[j] += w0 * b2f_s(r0[j]) + w1 * b2f_s(r1[j])
                    + w2 * b2f_s(r2[j]) + w3 * b2f_s(r3[j]);
        e += 8;
    }
    // tail: 2 edges per iteration (one per half), masked
    for (; e < e1; e += 2) {
        int idx = e + half;
        bool valid = idx < e1;
        long long pr = cs[valid ? idx : e];
        float w = valid ? __builtin_bit_cast(float, (int)(pr >> 32)) : 0.f;
        shortx8 r = *(const shortx8*)&hin[(size_t)(int)pr * H + f];
        ws += w;
        #pragma unroll
        for (int j = 0; j < 8; ++j) acc[j] += w * b2f_s(r[j]);
    }
    #pragma unroll
    for (int j = 0; j < 8; ++j) acc[j] += __shfl_xor(acc[j], 32, 64);
    ws += __shfl_xor(ws, 32, 64);
    if (half == 0 && active) {
        float4 bi0 = *(const float4*)&bias[f];
        float4 bi1 = *(const float4*)&bias[f + 4];
        if (cvec) {
            float4 c0 = *(const float4*)&cvec[f];
            float4 c1 = *(const float4*)&cvec[f + 4];
            bi0.x += ws * c0.x; bi0.y += ws * c0.y;
            bi0.z += ws * c0.z; bi0.w += ws * c0.w;
            bi1.x += ws * c1.x; bi1.y += ws * c1.y;
            bi1.z += ws * c1.z; bi1.w += ws * c1.w;
        }
        float z[8];
        z[0] = acc[0] + bi0.x; z[1] = acc[1] + bi0.y;
        z[2] = acc[2] + bi0.z; z[3] = acc[3] + bi0.w;
        z[4] = acc[4] + bi1.x; z[5] = acc[5] + bi1.y;
        z[6] = acc[6] + bi1.z; z[7] = acc[7] + bi1.w;
        shortx8 o;
        #pragma unroll
        for (int j = 0; j < 8; ++j) o[j] = (short)f2b(z[j]);
        *(shortx8*)&hout[(size_t)node * H + f] = o;
        if (stats) {
            #pragma unroll
            for (int j = 0; j < 8; ++j) {
                atomicAdd(&ls[f + j], z[j]);
                atomicAdd(&lq[f + j], z[j] * z[j]);
            }
        }
    }
    if (stats) {
        __syncthreads();
        int rep = (blockIdx.x & 63) * 256;
        atomicAdd(&colsum[rep + t], ls[t]);
        atomicAdd(&colsq[rep + t],  lq[t]);
    }
}

// ---------- head: BN2 affine + [256x5] dense + sigmoid, 4 nodes per block ----------
__global__ __launch_bounds__(256)
void k_head(const unsigned short* __restrict__ h, const float* __restrict__ a,
            const float* __restrict__ b, const float* __restrict__ Wd,
            const float* __restrict__ bd, float* __restrict__ out, int N) {
    int node = blockIdx.x * 4 + (threadIdx.x >> 6);
    if (node >= N) return;
    int lane = threadIdx.x & 63;
    int f = lane * 4;
    shortx4 hv = *(const shortx4*)&h[(size_t)node * 256 + f];
    float v0 = b2f_s(hv[0]) * a[f + 0] + b[f + 0];
    float v1 = b2f_s(hv[1]) * a[f + 1] + b[f + 1];
    float v2 = b2f_s(hv[2]) * a[f + 2] + b[f + 2];
    float v3 = b2f_s(hv[3]) * a[f + 3] + b[f + 3];
    float s[5];
    #pragma unroll
    for (int j = 0; j < 5; ++j) {
        s[j] = v0 * Wd[(f + 0) * 5 + j] + v1 * Wd[(f + 1) * 5 + j] +
               v2 * Wd[(f + 2) * 5 + j] + v3 * Wd[(f + 3) * 5 + j];
    }
    #pragma unroll
    for (int off = 32; off > 0; off >>= 1) {
        #pragma unroll
        for (int j = 0; j < 5; ++j) s[j] += __shfl_down(s[j], off, 64);
    }
    if (lane == 0) {
        #pragma unroll
        for (int j = 0; j < 5; ++j) {
            float z = s[j] + bd[j];
            out[(size_t)node * 5 + j] = 1.f / (1.f + expf(-z));
        }
    }
}

extern "C" void kernel_launch(void* const* d_in, const int* in_sizes, int n_in,
                              void* d_out, int out_size, void* d_ws, size_t ws_size,
                              hipStream_t stream) {
    const float* x      = (const float*)d_in[0];
    const void*  ei_raw = d_in[1];
    const float* gamma1 = (const float*)d_in[2];
    const float* beta1  = (const float*)d_in[3];
    const float* W1 = (const float*)d_in[4];
    const float* b1 = (const float*)d_in[5];
    const float* W2 = (const float*)d_in[6];
    const float* b2 = (const float*)d_in[7];
    const float* W3 = (const float*)d_in[8];
    const float* b3 = (const float*)d_in[9];
    const float* W4 = (const float*)d_in[10];
    const float* b4 = (const float*)d_in[11];
    const float* gamma2 = (const float*)d_in[12];
    const float* beta2  = (const float*)d_in[13];
    const float* Wd = (const float*)d_in[14];
    const float* bd = (const float*)d_in[15];

    const int F = in_sizes[2];        // 512
    const int N = in_sizes[0] / F;    // 50000
    const int E = in_sizes[1] / 2;    // 800000
    const int H = in_sizes[5];        // 256
    const int Mpad = ((N + 127) / 128) * 128;   // 50048
    const int NB   = (N + 1023) / 1024;
    float* out = (float*)d_out;

    char* p = (char*)d_ws;
    auto alloc = [&](size_t bytes) {
        void* r = (void*)p;
        p += (bytes + 255) & ~(size_t)255;
        return r;
    };
    int*   flag    = (int*)  alloc(4);
    int*   srcA    = (int*)  alloc((size_t)E * 4);
    int*   dstA    = (int*)  alloc((size_t)E * 4);
    // ---- contiguous zero-init group ----
    char*  zstart  = p;
    int*   cnt     = (int*)  alloc((size_t)N * 4);
    float* colsum8 = (float*)alloc((size_t)8 * F * 4);
    float* colsq8  = (float*)alloc((size_t)8 * F * 4);
    float* colsum2 = (float*)alloc((size_t)64 * H * 4);   // 64 replicas (agg4-fused stats)
    float* colsq2  = (float*)alloc((size_t)64 * H * 4);
    float* cvec    = (float*)alloc((size_t)H * 4);
    size_t zbytes  = (size_t)(p - zstart);
    int*   row_ptr = (int*)  alloc(((size_t)N + 1) * 4);
    int*   cursor  = (int*)  alloc((size_t)N * 4);
    float* dinv    = (float*)alloc((size_t)N * 4);
    int2*  csr_sw  = (int2*) alloc((size_t)E * 8);
    int*   bsum    = (int*)  alloc((size_t)NB * 4);
    float* bna     = (float*)alloc((size_t)F * 4);
    float* bnb     = (float*)alloc((size_t)F * 4);
    unsigned short* W1t = (unsigned short*)alloc((size_t)F * H * 2);
    unsigned short* W2t = (unsigned short*)alloc((size_t)H * H * 2);
    unsigned short* W3t = (unsigned short*)alloc((size_t)H * H * 2);
    unsigned short* W4t = (unsigned short*)alloc((size_t)H * H * 2);
    unsigned short* xb  = (unsigned short*)alloc((size_t)Mpad * F * 2);
    unsigned short* hbA = (unsigned short*)alloc((size_t)Mpad * H * 2);
    unsigned short* hbB = (unsigned short*)alloc((size_t)Mpad * H * 2);

    hipMemsetAsync(zstart, 0, zbytes, stream);
    // zero bf16 pad rows of xb
    hipMemsetAsync(xb + (size_t)N * F, 0, (size_t)(Mpad - N) * F * 2, stream);

    // graph build
    int n_check = (E >= 2048) ? 2048 : E;
    k_detect<<<1, 256, 0, stream>>>((const unsigned int*)ei_raw, n_check, flag);
    k_convert<<<(E + 255) / 256, 256, 0, stream>>>(ei_raw, flag, srcA, dstA, cnt, E);
    k_scan_sum<<<NB, 1024, 0, stream>>>(cnt, bsum, N);
    k_scan_part<<<1, 1024, 0, stream>>>(bsum, NB);
    k_scan_final<<<NB, 1024, 0, stream>>>(cnt, bsum, row_ptr, cursor, dinv, N);
    k_fill<<<(E + 255) / 256, 256, 0, stream>>>(srcA, dstA, cursor, dinv, csr_sw, E);

    // BN1 stats + raw cast (single pass over x)
    int NQ = N * (F >> 2);
    k_bnstats_cast<<<2048, 256, 0, stream>>>(x, xb, colsum8, colsq8, NQ, F);
    k_bnfin<<<(F + 255) / 256, 256, 0, stream>>>(colsum8, colsq8, gamma1, beta1, bna, bnb, N, F, 8);

    // weight casts (W1 scaled by bna) + cvec = bnb^T @ W1
    int tot = F * H + 3 * H * H;
    k_castWT4<<<(tot + 255) / 256, 256, 0, stream>>>(W1, W2, W3, W4, W1t, W2t, W3t, W4t, bna, F, H);
    k_cvec<<<8, 256, 0, stream>>>(W1, bnb, cvec, F, H);

    dim3 gg(Mpad / 128, H / 128);
    int aggb = (N + 3) / 4;
    // conv1 (BN1 folded: xb raw, W1t pre-scaled, cvec correction via wsum)
    k_gemm_bf16<<<gg, 256, 0, stream>>>(xb, W1t, hbA, F, H);
    k_agg<<<aggb, 256, 0, stream>>>(hbA, hbB, row_ptr, csr_sw, dinv, b1, cvec, N, nullptr, nullptr);
    // conv2
    k_gemm_bf16<<<gg, 256, 0, stream>>>(hbB, W2t, hbA, H, H);
    k_agg<<<aggb, 256, 0, stream>>>(hbA, hbB, row_ptr, csr_sw, dinv, b2, nullptr, N, nullptr, nullptr);
    // conv3
    k_gemm_bf16<<<gg, 256, 0, stream>>>(hbB, W3t, hbA, H, H);
    k_agg<<<aggb, 256, 0, stream>>>(hbA, hbB, row_ptr, csr_sw, dinv, b3, nullptr, N, nullptr, nullptr);
    // conv4 (+ fused BN2 column stats on exact f32 values)
    k_gemm_bf16<<<gg, 256, 0, stream>>>(hbB, W4t, hbA, H, H);
    k_agg<<<aggb, 256, 0, stream>>>(hbA, hbB, row_ptr, csr_sw, dinv, b4, nullptr, N, colsum2, colsq2);

    // BN2 finalize + head (bnstats_b pass eliminated)
    k_bnfin<<<(H + 255) / 256, 256, 0, stream>>>(colsum2, colsq2, gamma2, beta2, bna, bnb, N, H, 64);
    k_head<<<(N + 3) / 4, 256, 0, stream>>>(hbB, bna, bnb, Wd, bd, out, N);
}

// Round 8
// 684.216 us; speedup vs baseline: 1.1359x; 1.1359x over previous
//
#include <hip/hip_runtime.h>
#include <math.h>

#define BN_EPS 1e-5f

typedef float floatx4 __attribute__((ext_vector_type(4)));
typedef short shortx4 __attribute__((ext_vector_type(4)));
typedef short shortx8 __attribute__((ext_vector_type(8)));
typedef __bf16 bf16x8 __attribute__((ext_vector_type(8)));

// ---- bf16 helpers (RNE, branch-free; no NaNs in this workload) ----
__device__ __forceinline__ unsigned short f2b(float f) {
    unsigned int u = __builtin_bit_cast(unsigned int, f);
    u += 0x7fffu + ((u >> 16) & 1u);
    return (unsigned short)(u >> 16);
}
__device__ __forceinline__ float b2f(unsigned short s) {
    unsigned int u = ((unsigned int)s) << 16;
    return __builtin_bit_cast(float, u);
}
__device__ __forceinline__ float b2f_s(short s) { return b2f((unsigned short)s); }

// ---------- edge-index layout detection (int32 vs int64 storage) ----------
__global__ __launch_bounds__(256)
void k_detect(const unsigned int* __restrict__ ei, int n_check, int* __restrict__ flag) {
    __shared__ int any;
    if (threadIdx.x == 0) any = 0;
    __syncthreads();
    for (int i = threadIdx.x; i < n_check; i += 256) {
        if (ei[2 * i + 1] != 0u) any = 1;
    }
    __syncthreads();
    if (threadIdx.x == 0) *flag = any;   // 1 => int32 layout, 0 => int64 layout
}

// ---------- convert + degree count fused ----------
__global__ __launch_bounds__(256)
void k_convert(const void* __restrict__ ei_raw, const int* __restrict__ flag,
               int* __restrict__ src, int* __restrict__ dst, int* __restrict__ cnt, int E) {
    int e = blockIdx.x * 256 + threadIdx.x;
    if (e >= E) return;
    int s, d;
    if (*flag) {
        const int* a = (const int*)ei_raw;
        s = a[e]; d = a[E + e];
    } else {
        const long long* a = (const long long*)ei_raw;
        s = (int)a[e]; d = (int)a[E + e];
    }
    src[e] = s;
    dst[e] = d;
    atomicAdd(&cnt[d], 1);
}

// ---------- 3-phase parallel exclusive scan ----------
__global__ __launch_bounds__(1024)
void k_scan_sum(const int* __restrict__ cnt, int* __restrict__ bsum, int N) {
    __shared__ int s[1024];
    int i = blockIdx.x * 1024 + threadIdx.x;
    s[threadIdx.x] = (i < N) ? cnt[i] : 0;
    __syncthreads();
    for (int off = 512; off > 0; off >>= 1) {
        if (threadIdx.x < off) s[threadIdx.x] += s[threadIdx.x + off];
        __syncthreads();
    }
    if (threadIdx.x == 0) bsum[blockIdx.x] = s[0];
}

__global__ __launch_bounds__(1024)
void k_scan_part(int* __restrict__ bsum, int nb) {
    __shared__ int s[1024];
    int t = threadIdx.x;
    int v = (t < nb) ? bsum[t] : 0;
    s[t] = v;
    __syncthreads();
    for (int off = 1; off < 1024; off <<= 1) {
        int tmp = (t >= off) ? s[t - off] : 0;
        __syncthreads();
        s[t] += tmp;
        __syncthreads();
    }
    if (t < nb) bsum[t] = s[t] - v;     // exclusive
}

__global__ __launch_bounds__(1024)
void k_scan_final(const int* __restrict__ cnt, const int* __restrict__ bsum,
                  int* __restrict__ row_ptr, int* __restrict__ cursor,
                  float* __restrict__ dinv, int N) {
    __shared__ int s[1024];
    int b = blockIdx.x, t = threadIdx.x;
    int i = b * 1024 + t;
    int v = (i < N) ? cnt[i] : 0;
    s[t] = v;
    __syncthreads();
    for (int off = 1; off < 1024; off <<= 1) {
        int tmp = (t >= off) ? s[t - off] : 0;
        __syncthreads();
        s[t] += tmp;
        __syncthreads();
    }
    if (i < N) {
        int excl = bsum[b] + s[t] - v;
        row_ptr[i] = excl;
        cursor[i]  = excl;
        dinv[i] = rsqrtf((float)(v + 1));
        if (i == N - 1) row_ptr[N] = excl + v;
    }
}

// ---------- CSR fill: packed (src, weight) pairs ----------
__global__ __launch_bounds__(256)
void k_fill(const int* __restrict__ src, const int* __restrict__ dst,
            int* __restrict__ cursor, const float* __restrict__ dinv,
            int2* __restrict__ csr_sw, int E) {
    int e = blockIdx.x * 256 + threadIdx.x;
    if (e >= E) return;
    int s = src[e], d = dst[e];
    int p = atomicAdd(&cursor[d], 1);
    float w = dinv[s] * dinv[d];
    csr_sw[p] = make_int2(s, __builtin_bit_cast(int, w));
}

// ---------- fused BN1 stats + raw bf16 cast of x (x read ONCE) ----------
// Flat grid-stride over float4 quads, exact bulk region with unconditional
// 4-deep unroll. NT loads: x is dead after this kernel.
__global__ __launch_bounds__(256)
void k_bnstats_cast(const float* __restrict__ x, unsigned short* __restrict__ xb,
                    float* __restrict__ sum8, float* __restrict__ sumsq8,
                    int NQ, int F) {
    __shared__ float ls[512], lq[512];
    int t   = threadIdx.x;
    int tid = blockIdx.x * 256 + t;
    int G   = gridDim.x * 256;           // multiple of F/4
    int cq  = tid & ((F >> 2) - 1);      // column quad, invariant over the stride
    const floatx4* xv = (const floatx4*)x;
    shortx4* xo = (shortx4*)xb;

    float s0 = 0.f, s1 = 0.f, s2 = 0.f, s3 = 0.f;
    float q0 = 0.f, q1 = 0.f, q2 = 0.f, q3 = 0.f;

    int G4 = G << 2;
    int Qfull = NQ - (NQ % G4);
    int i = tid;
    for (; i < Qfull; i += G4) {
        floatx4 a = __builtin_nontemporal_load(&xv[i]);
        floatx4 b = __builtin_nontemporal_load(&xv[i + G]);
        floatx4 c = __builtin_nontemporal_load(&xv[i + 2 * G]);
        floatx4 d = __builtin_nontemporal_load(&xv[i + 3 * G]);
        shortx4 o;
        o[0] = (short)f2b(a[0]); o[1] = (short)f2b(a[1]);
        o[2] = (short)f2b(a[2]); o[3] = (short)f2b(a[3]);
        xo[i] = o;
        s0 += a[0]; s1 += a[1]; s2 += a[2]; s3 += a[3];
        q0 += a[0] * a[0]; q1 += a[1] * a[1]; q2 += a[2] * a[2]; q3 += a[3] * a[3];
        o[0] = (short)f2b(b[0]); o[1] = (short)f2b(b[1]);
        o[2] = (short)f2b(b[2]); o[3] = (short)f2b(b[3]);
        xo[i + G] = o;
        s0 += b[0]; s1 += b[1]; s2 += b[2]; s3 += b[3];
        q0 += b[0] * b[0]; q1 += b[1] * b[1]; q2 += b[2] * b[2]; q3 += b[3] * b[3];
        o[0] = (short)f2b(c[0]); o[1] = (short)f2b(c[1]);
        o[2] = (short)f2b(c[2]); o[3] = (short)f2b(c[3]);
        xo[i + 2 * G] = o;
        s0 += c[0]; s1 += c[1]; s2 += c[2]; s3 += c[3];
        q0 += c[0] * c[0]; q1 += c[1] * c[1]; q2 += c[2] * c[2]; q3 += c[3] * c[3];
        o[0] = (short)f2b(d[0]); o[1] = (short)f2b(d[1]);
        o[2] = (short)f2b(d[2]); o[3] = (short)f2b(d[3]);
        xo[i + 3 * G] = o;
        s0 += d[0]; s1 += d[1]; s2 += d[2]; s3 += d[3];
        q0 += d[0] * d[0]; q1 += d[1] * d[1]; q2 += d[2] * d[2]; q3 += d[3] * d[3];
    }
    for (; i < NQ; i += G) {
        floatx4 a = __builtin_nontemporal_load(&xv[i]);
        shortx4 o;
        o[0] = (short)f2b(a[0]); o[1] = (short)f2b(a[1]);
        o[2] = (short)f2b(a[2]); o[3] = (short)f2b(a[3]);
        xo[i] = o;
        s0 += a[0]; s1 += a[1]; s2 += a[2]; s3 += a[3];
        q0 += a[0] * a[0]; q1 += a[1] * a[1]; q2 += a[2] * a[2]; q3 += a[3] * a[3];
    }

    for (int c = t; c < F; c += 256) { ls[c] = 0.f; lq[c] = 0.f; }
    __syncthreads();
    atomicAdd(&ls[cq * 4 + 0], s0); atomicAdd(&ls[cq * 4 + 1], s1);
    atomicAdd(&ls[cq * 4 + 2], s2); atomicAdd(&ls[cq * 4 + 3], s3);
    atomicAdd(&lq[cq * 4 + 0], q0); atomicAdd(&lq[cq * 4 + 1], q1);
    atomicAdd(&lq[cq * 4 + 2], q2); atomicAdd(&lq[cq * 4 + 3], q3);
    __syncthreads();
    int rep = (blockIdx.x & 7) * F;
    for (int c = t; c < F; c += 256) {
        atomicAdd(&sum8[rep + c],   ls[c]);
        atomicAdd(&sumsq8[rep + c], lq[c]);
    }
}

// ---------- batchnorm column stats on bf16 input (H=256), 4 replicas ----------
// Flat grid-stride; plain loads (hbB is L2-warm from k_agg stores).
__global__ __launch_bounds__(256)
void k_bnstats_b(const unsigned short* __restrict__ x, float* __restrict__ sum,
                 float* __restrict__ sumsq, int NG, int H) {
    __shared__ float ls[256], lq[256];
    int t   = threadIdx.x;
    int tid = blockIdx.x * 256 + t;
    int G   = gridDim.x * 256;           // multiple of H/8
    int cg  = tid & ((H >> 3) - 1);      // group-in-row, invariant
    const shortx8* xv = (const shortx8*)x;
    float s[8], q[8];
    #pragma unroll
    for (int j = 0; j < 8; ++j) { s[j] = 0.f; q[j] = 0.f; }

    int G2 = G << 1;
    int Qfull = NG - (NG % G2);
    int i = tid;
    for (; i < Qfull; i += G2) {
        shortx8 a = xv[i];
        shortx8 b = xv[i + G];
        #pragma unroll
        for (int j = 0; j < 8; ++j) {
            float fa = b2f_s(a[j]);
            float fb = b2f_s(b[j]);
            s[j] += fa + fb;
            q[j] += fa * fa + fb * fb;
        }
    }
    for (; i < NG; i += G) {
        shortx8 a = xv[i];
        #pragma unroll
        for (int j = 0; j < 8; ++j) {
            float fa = b2f_s(a[j]);
            s[j] += fa; q[j] += fa * fa;
        }
    }

    ls[t] = 0.f; lq[t] = 0.f;
    __syncthreads();
    #pragma unroll
    for (int j = 0; j < 8; ++j) {
        atomicAdd(&ls[cg * 8 + j], s[j]);
        atomicAdd(&lq[cg * 8 + j], q[j]);
    }
    __syncthreads();
    int rep = (blockIdx.x & 3) * H;
    atomicAdd(&sum[rep + t],   ls[t]);
    atomicAdd(&sumsq[rep + t], lq[t]);
}

// ---------- finalize BN affine from nrep replicated partials ----------
__global__ __launch_bounds__(256)
void k_bnfin(const float* __restrict__ sum, const float* __restrict__ sumsq,
             const float* __restrict__ gamma, const float* __restrict__ beta,
             float* __restrict__ a, float* __restrict__ b, int N, int F, int nrep) {
    int c = blockIdx.x * 256 + threadIdx.x;
    if (c >= F) return;
    float s = 0.f, ss = 0.f;
    for (int i = 0; i < nrep; ++i) { s += sum[i * F + c]; ss += sumsq[i * F + c]; }
    float m   = s / (float)N;
    float var = ss / (float)N - m * m;
    float rs  = rsqrtf(var + BN_EPS);
    float aa  = gamma[c] * rs;
    a[c] = aa;
    b[c] = beta[c] - m * aa;
}

// ---------- cast + transpose all 4 weights; W1 scaled by BN1 a[k] ----------
__global__ __launch_bounds__(256)
void k_castWT4(const float* __restrict__ W1, const float* __restrict__ W2,
               const float* __restrict__ W3, const float* __restrict__ W4,
               unsigned short* __restrict__ T1, unsigned short* __restrict__ T2,
               unsigned short* __restrict__ T3, unsigned short* __restrict__ T4,
               const float* __restrict__ bna, int F, int H) {
    int i = blockIdx.x * 256 + threadIdx.x;
    int n1 = F * H, n2 = H * H;
    if (i < n1) {
        int n = i / F, k = i % F;
        T1[i] = f2b(W1[(size_t)k * H + n] * bna[k]);
        return;
    }
    const float* W; unsigned short* T; int j;
    if (i < n1 + n2)          { W = W2; T = T2; j = i - n1; }
    else if (i < n1 + 2 * n2) { W = W3; T = T3; j = i - n1 - n2; }
    else if (i < n1 + 3 * n2) { W = W4; T = T4; j = i - n1 - 2 * n2; }
    else return;
    int n = j / H, k = j % H;
    T[j] = f2b(W[(size_t)k * H + n]);
}

// ---------- cvec: c_j = sum_k bnb[k] * W1[k,j]  (BN1 shift folded through GEMM1) ----------
__global__ __launch_bounds__(256)
void k_cvec(const float* __restrict__ W1, const float* __restrict__ bnb,
            float* __restrict__ cvec, int F, int H) {
    int j = threadIdx.x;           // H == 256 == blockDim
    int kslice = F / 8;
    int k0 = blockIdx.x * kslice;
    float s = 0.f;
    for (int k = k0; k < k0 + kslice; ++k)
        s += bnb[k] * W1[(size_t)k * H + j];
    atomicAdd(&cvec[j], s);
}

// ---------- bf16 MFMA GEMM: C[M,NC] = A[M,K] @ Wt[NC,K]^T ----------
__device__ __forceinline__ void glds16(const void* g, void* l) {
    __builtin_amdgcn_global_load_lds(
        (const __attribute__((address_space(1))) unsigned int*)g,
        (__attribute__((address_space(3))) unsigned int*)l, 16, 0, 0);
}

__global__ __launch_bounds__(256)
void k_gemm_bf16(const unsigned short* __restrict__ A, const unsigned short* __restrict__ Bt,
                 unsigned short* __restrict__ C, int K, int NC) {
    __shared__ unsigned short As[128 * 32];
    __shared__ unsigned short Bs[128 * 32];
    int tid  = threadIdx.x;
    int wave = tid >> 6, lane = tid & 63;
    int row0 = blockIdx.x * 128;
    int col0 = blockIdx.y * 128;
    int wr = (wave & 1) * 64;
    int wc = (wave >> 1) * 64;

    floatx4 acc[4][4];
    #pragma unroll
    for (int i = 0; i < 4; i++)
        #pragma unroll
        for (int j = 0; j < 4; j++) acc[i][j] = (floatx4){0.f, 0.f, 0.f, 0.f};

    int cA = tid * 16;
    int cB = cA + 4096;
    const char* Ab = (const char*)A;
    const char* Bb = (const char*)Bt;
    size_t a_off0 = (size_t)(row0 + (cA >> 6)) * K * 2 + (cA & 63);
    size_t a_off1 = (size_t)(row0 + (cB >> 6)) * K * 2 + (cB & 63);
    size_t b_off0 = (size_t)(col0 + (cA >> 6)) * K * 2 + (cA & 63);
    size_t b_off1 = (size_t)(col0 + (cB >> 6)) * K * 2 + (cB & 63);

    int lm  = lane & 15;
    int lk8 = (lane >> 4) * 8;

    for (int ks = 0; ks < K; ks += 32) {
        size_t koff = (size_t)ks * 2;
        glds16(Ab + a_off0 + koff, (char*)As + cA);
        glds16(Ab + a_off1 + koff, (char*)As + cA + 4096);
        glds16(Bb + b_off0 + koff, (char*)Bs + cA);
        glds16(Bb + b_off1 + koff, (char*)Bs + cA + 4096);
        __syncthreads();

        bf16x8 af[4], bfr[4];
        #pragma unroll
        for (int i = 0; i < 4; i++) {
            shortx8 s = *(const shortx8*)&As[(wr + i * 16 + lm) * 32 + lk8];
            af[i] = __builtin_bit_cast(bf16x8, s);
        }
        #pragma unroll
        for (int j = 0; j < 4; j++) {
            shortx8 s = *(const shortx8*)&Bs[(wc + j * 16 + lm) * 32 + lk8];
            bfr[j] = __builtin_bit_cast(bf16x8, s);
        }
        #pragma unroll
        for (int i = 0; i < 4; i++)
            #pragma unroll
            for (int j = 0; j < 4; j++)
                acc[i][j] = __builtin_amdgcn_mfma_f32_16x16x32_bf16(af[i], bfr[j], acc[i][j], 0, 0, 0);
        __syncthreads();
    }

    int crow = row0 + wr + (lane >> 4) * 4;
    int ccol = col0 + wc + lm;
    #pragma unroll
    for (int i = 0; i < 4; i++)
        #pragma unroll
        for (int j = 0; j < 4; j++)
            #pragma unroll
            for (int r = 0; r < 4; r++)
                C[(size_t)(crow + i * 16 + r) * NC + ccol + j * 16] = f2b(acc[i][j][r]);
}

// ---------- CSR gather-aggregation: wave per node, half-wave owns 8 contiguous
// edges per iteration. Plain cached loads/stores (CSR reused 4x across layers;
// hout feeds the next GEMM). Proven-best structure (round 5: 60.3 us/layer,
// BW-bound at 3.6 TB/s on random 512B gathers, MLP-insensitive).
__global__ __launch_bounds__(256)
void k_agg(const unsigned short* __restrict__ hin, unsigned short* __restrict__ hout,
           const int* __restrict__ row_ptr, const int2* __restrict__ csr_sw,
           const float* __restrict__ dinv, const float* __restrict__ bias,
           const float* __restrict__ cvec, int N) {
    const int H = 256;
    int node = blockIdx.x * 4 + (threadIdx.x >> 6);
    if (node >= N) return;
    int lane = threadIdx.x & 63;
    int half = lane >> 5;
    int f = (lane & 31) * 8;
    float acc[8];
    float ws;
    float di = dinv[node];
    if (half == 0) {
        shortx8 hv = *(const shortx8*)&hin[(size_t)node * H + f];
        float sl = di * di;
        ws = sl;
        #pragma unroll
        for (int j = 0; j < 8; ++j) acc[j] = b2f_s(hv[j]) * sl;
    } else {
        ws = 0.f;
        #pragma unroll
        for (int j = 0; j < 8; ++j) acc[j] = 0.f;
    }
    int e0 = row_ptr[node], e1 = row_ptr[node + 1];
    const long long* cs = (const long long*)csr_sw;
    int e = e0;
    // bulk: 16 edges per iteration, half-wave takes 8 contiguous
    for (; e + 16 <= e1; e += 16) {
        int base = e + half * 8;
        long long p0 = cs[base + 0];
        long long p1 = cs[base + 1];
        long long p2 = cs[base + 2];
        long long p3 = cs[base + 3];
        long long p4 = cs[base + 4];
        long long p5 = cs[base + 5];
        long long p6 = cs[base + 6];
        long long p7 = cs[base + 7];
        shortx8 r0 = *(const shortx8*)&hin[(size_t)(int)p0 * H + f];
        shortx8 r1 = *(const shortx8*)&hin[(size_t)(int)p1 * H + f];
        shortx8 r2 = *(const shortx8*)&hin[(size_t)(int)p2 * H + f];
        shortx8 r3 = *(const shortx8*)&hin[(size_t)(int)p3 * H + f];
        shortx8 r4 = *(const shortx8*)&hin[(size_t)(int)p4 * H + f];
        shortx8 r5 = *(const shortx8*)&hin[(size_t)(int)p5 * H + f];
        shortx8 r6 = *(const shortx8*)&hin[(size_t)(int)p6 * H + f];
        shortx8 r7 = *(const shortx8*)&hin[(size_t)(int)p7 * H + f];
        float w0 = __builtin_bit_cast(float, (int)(p0 >> 32));
        float w1 = __builtin_bit_cast(float, (int)(p1 >> 32));
        float w2 = __builtin_bit_cast(float, (int)(p2 >> 32));
        float w3 = __builtin_bit_cast(float, (int)(p3 >> 32));
        float w4 = __builtin_bit_cast(float, (int)(p4 >> 32));
        float w5 = __builtin_bit_cast(float, (int)(p5 >> 32));
        float w6 = __builtin_bit_cast(float, (int)(p6 >> 32));
        float w7 = __builtin_bit_cast(float, (int)(p7 >> 32));
        ws += ((w0 + w1) + (w2 + w3)) + ((w4 + w5) + (w6 + w7));
        #pragma unroll
        for (int j = 0; j < 8; ++j) {
            float t0 = w0 * b2f_s(r0[j]) + w1 * b2f_s(r1[j])
                     + w2 * b2f_s(r2[j]) + w3 * b2f_s(r3[j]);
            float t1 = w4 * b2f_s(r4[j]) + w5 * b2f_s(r5[j])
                     + w6 * b2f_s(r6[j]) + w7 * b2f_s(r7[j]);
            acc[j] += t0 + t1;
        }
    }
    // mid: one optional 8-edge step, half-wave takes 4 contiguous
    if (e + 8 <= e1) {
        int base = e + half * 4;
        long long p0 = cs[base + 0];
        long long p1 = cs[base + 1];
        long long p2 = cs[base + 2];
        long long p3 = cs[base + 3];
        shortx8 r0 = *(const shortx8*)&hin[(size_t)(int)p0 * H + f];
        shortx8 r1 = *(const shortx8*)&hin[(size_t)(int)p1 * H + f];
        shortx8 r2 = *(const shortx8*)&hin[(size_t)(int)p2 * H + f];
        shortx8 r3 = *(const shortx8*)&hin[(size_t)(int)p3 * H + f];
        float w0 = __builtin_bit_cast(float, (int)(p0 >> 32));
        float w1 = __builtin_bit_cast(float, (int)(p1 >> 32));
        float w2 = __builtin_bit_cast(float, (int)(p2 >> 32));
        float w3 = __builtin_bit_cast(float, (int)(p3 >> 32));
        ws += (w0 + w1) + (w2 + w3);
        #pragma unroll
        for (int j = 0; j < 8; ++j)
            acc[j] += w0 * b2f_s(r0[j]) + w1 * b2f_s(r1[j])
                    + w2 * b2f_s(r2[j]) + w3 * b2f_s(r3[j]);
        e += 8;
    }
    // tail: 2 edges per iteration (one per half), masked
    for (; e < e1; e += 2) {
        int idx = e + half;
        bool valid = idx < e1;
        long long pr = cs[valid ? idx : e];
        float w = valid ? __builtin_bit_cast(float, (int)(pr >> 32)) : 0.f;
        shortx8 r = *(const shortx8*)&hin[(size_t)(int)pr * H + f];
        ws += w;
        #pragma unroll
        for (int j = 0; j < 8; ++j) acc[j] += w * b2f_s(r[j]);
    }
    #pragma unroll
    for (int j = 0; j < 8; ++j) acc[j] += __shfl_xor(acc[j], 32, 64);
    ws += __shfl_xor(ws, 32, 64);
    if (half == 0) {
        float4 bi0 = *(const float4*)&bias[f];
        float4 bi1 = *(const float4*)&bias[f + 4];
        if (cvec) {
            float4 c0 = *(const float4*)&cvec[f];
            float4 c1 = *(const float4*)&cvec[f + 4];
            bi0.x += ws * c0.x; bi0.y += ws * c0.y;
            bi0.z += ws * c0.z; bi0.w += ws * c0.w;
            bi1.x += ws * c1.x; bi1.y += ws * c1.y;
            bi1.z += ws * c1.z; bi1.w += ws * c1.w;
        }
        shortx8 o;
        o[0] = (short)f2b(acc[0] + bi0.x);
        o[1] = (short)f2b(acc[1] + bi0.y);
        o[2] = (short)f2b(acc[2] + bi0.z);
        o[3] = (short)f2b(acc[3] + bi0.w);
        o[4] = (short)f2b(acc[4] + bi1.x);
        o[5] = (short)f2b(acc[5] + bi1.y);
        o[6] = (short)f2b(acc[6] + bi1.z);
        o[7] = (short)f2b(acc[7] + bi1.w);
        *(shortx8*)&hout[(size_t)node * H + f] = o;
    }
}

// ---------- head: BN2 affine + [256x5] dense + sigmoid, 4 nodes per block ----------
__global__ __launch_bounds__(256)
void k_head(const unsigned short* __restrict__ h, const float* __restrict__ a,
            const float* __restrict__ b, const float* __restrict__ Wd,
            const float* __restrict__ bd, float* __restrict__ out, int N) {
    int node = blockIdx.x * 4 + (threadIdx.x >> 6);
    if (node >= N) return;
    int lane = threadIdx.x & 63;
    int f = lane * 4;
    shortx4 hv = *(const shortx4*)&h[(size_t)node * 256 + f];
    float v0 = b2f_s(hv[0]) * a[f + 0] + b[f + 0];
    float v1 = b2f_s(hv[1]) * a[f + 1] + b[f + 1];
    float v2 = b2f_s(hv[2]) * a[f + 2] + b[f + 2];
    float v3 = b2f_s(hv[3]) * a[f + 3] + b[f + 3];
    float s[5];
    #pragma unroll
    for (int j = 0; j < 5; ++j) {
        s[j] = v0 * Wd[(f + 0) * 5 + j] + v1 * Wd[(f + 1) * 5 + j] +
               v2 * Wd[(f + 2) * 5 + j] + v3 * Wd[(f + 3) * 5 + j];
    }
    #pragma unroll
    for (int off = 32; off > 0; off >>= 1) {
        #pragma unroll
        for (int j = 0; j < 5; ++j) s[j] += __shfl_down(s[j], off, 64);
    }
    if (lane == 0) {
        #pragma unroll
        for (int j = 0; j < 5; ++j) {
            float z = s[j] + bd[j];
            out[(size_t)node * 5 + j] = 1.f / (1.f + expf(-z));
        }
    }
}

extern "C" void kernel_launch(void* const* d_in, const int* in_sizes, int n_in,
                              void* d_out, int out_size, void* d_ws, size_t ws_size,
                              hipStream_t stream) {
    const float* x      = (const float*)d_in[0];
    const void*  ei_raw = d_in[1];
    const float* gamma1 = (const float*)d_in[2];
    const float* beta1  = (const float*)d_in[3];
    const float* W1 = (const float*)d_in[4];
    const float* b1 = (const float*)d_in[5];
    const float* W2 = (const float*)d_in[6];
    const float* b2 = (const float*)d_in[7];
    const float* W3 = (const float*)d_in[8];
    const float* b3 = (const float*)d_in[9];
    const float* W4 = (const float*)d_in[10];
    const float* b4 = (const float*)d_in[11];
    const float* gamma2 = (const float*)d_in[12];
    const float* beta2  = (const float*)d_in[13];
    const float* Wd = (const float*)d_in[14];
    const float* bd = (const float*)d_in[15];

    const int F = in_sizes[2];        // 512
    const int N = in_sizes[0] / F;    // 50000
    const int E = in_sizes[1] / 2;    // 800000
    const int H = in_sizes[5];        // 256
    const int Mpad = ((N + 127) / 128) * 128;   // 50048
    const int NB   = (N + 1023) / 1024;
    float* out = (float*)d_out;

    char* p = (char*)d_ws;
    auto alloc = [&](size_t bytes) {
        void* r = (void*)p;
        p += (bytes + 255) & ~(size_t)255;
        return r;
    };
    int*   flag    = (int*)  alloc(4);
    int*   srcA    = (int*)  alloc((size_t)E * 4);
    int*   dstA    = (int*)  alloc((size_t)E * 4);
    // ---- contiguous zero-init group ----
    char*  zstart  = p;
    int*   cnt     = (int*)  alloc((size_t)N * 4);
    float* colsum8 = (float*)alloc((size_t)8 * F * 4);
    float* colsq8  = (float*)alloc((size_t)8 * F * 4);
    float* colsum2 = (float*)alloc((size_t)4 * H * 4);
    float* colsq2  = (float*)alloc((size_t)4 * H * 4);
    float* cvec    = (float*)alloc((size_t)H * 4);
    size_t zbytes  = (size_t)(p - zstart);
    int*   row_ptr = (int*)  alloc(((size_t)N + 1) * 4);
    int*   cursor  = (int*)  alloc((size_t)N * 4);
    float* dinv    = (float*)alloc((size_t)N * 4);
    int2*  csr_sw  = (int2*) alloc((size_t)E * 8);
    int*   bsum    = (int*)  alloc((size_t)NB * 4);
    float* bna     = (float*)alloc((size_t)F * 4);
    float* bnb     = (float*)alloc((size_t)F * 4);
    unsigned short* W1t = (unsigned short*)alloc((size_t)F * H * 2);
    unsigned short* W2t = (unsigned short*)alloc((size_t)H * H * 2);
    unsigned short* W3t = (unsigned short*)alloc((size_t)H * H * 2);
    unsigned short* W4t = (unsigned short*)alloc((size_t)H * H * 2);
    unsigned short* xb  = (unsigned short*)alloc((size_t)Mpad * F * 2);
    unsigned short* hbA = (unsigned short*)alloc((size_t)Mpad * H * 2);
    unsigned short* hbB = (unsigned short*)alloc((size_t)Mpad * H * 2);

    hipMemsetAsync(zstart, 0, zbytes, stream);
    // zero bf16 pad rows of xb
    hipMemsetAsync(xb + (size_t)N * F, 0, (size_t)(Mpad - N) * F * 2, stream);

    // graph build
    int n_check = (E >= 2048) ? 2048 : E;
    k_detect<<<1, 256, 0, stream>>>((const unsigned int*)ei_raw, n_check, flag);
    k_convert<<<(E + 255) / 256, 256, 0, stream>>>(ei_raw, flag, srcA, dstA, cnt, E);
    k_scan_sum<<<NB, 1024, 0, stream>>>(cnt, bsum, N);
    k_scan_part<<<1, 1024, 0, stream>>>(bsum, NB);
    k_scan_final<<<NB, 1024, 0, stream>>>(cnt, bsum, row_ptr, cursor, dinv, N);
    k_fill<<<(E + 255) / 256, 256, 0, stream>>>(srcA, dstA, cursor, dinv, csr_sw, E);

    // BN1 stats + raw cast (single pass over x)
    int NQ = N * (F >> 2);
    k_bnstats_cast<<<2048, 256, 0, stream>>>(x, xb, colsum8, colsq8, NQ, F);
    k_bnfin<<<(F + 255) / 256, 256, 0, stream>>>(colsum8, colsq8, gamma1, beta1, bna, bnb, N, F, 8);

    // weight casts (W1 scaled by bna) + cvec = bnb^T @ W1
    int tot = F * H + 3 * H * H;
    k_castWT4<<<(tot + 255) / 256, 256, 0, stream>>>(W1, W2, W3, W4, W1t, W2t, W3t, W4t, bna, F, H);
    k_cvec<<<8, 256, 0, stream>>>(W1, bnb, cvec, F, H);

    dim3 gg(Mpad / 128, H / 128);
    int aggb = (N + 3) / 4;
    // conv1 (BN1 folded: xb raw, W1t pre-scaled, cvec correction via wsum)
    k_gemm_bf16<<<gg, 256, 0, stream>>>(xb, W1t, hbA, F, H);
    k_agg<<<aggb, 256, 0, stream>>>(hbA, hbB, row_ptr, csr_sw, dinv, b1, cvec, N);
    // conv2
    k_gemm_bf16<<<gg, 256, 0, stream>>>(hbB, W2t, hbA, H, H);
    k_agg<<<aggb, 256, 0, stream>>>(hbA, hbB, row_ptr, csr_sw, dinv, b2, nullptr, N);
    // conv3
    k_gemm_bf16<<<gg, 256, 0, stream>>>(hbB, W3t, hbA, H, H);
    k_agg<<<aggb, 256, 0, stream>>>(hbA, hbB, row_ptr, csr_sw, dinv, b3, nullptr, N);
    // conv4
    k_gemm_bf16<<<gg, 256, 0, stream>>>(hbB, W4t, hbA, H, H);
    k_agg<<<aggb, 256, 0, stream>>>(hbA, hbB, row_ptr, csr_sw, dinv, b4, nullptr, N);

    // BN2 + head
    int NG = N * (H >> 3);
    k_bnstats_b<<<1024, 256, 0, stream>>>(hbB, colsum2, colsq2, NG, H);
    k_bnfin<<<(H + 255) / 256, 256, 0, stream>>>(colsum2, colsq2, gamma2, beta2, bna, bnb, N, H, 4);
    k_head<<<(N + 3) / 4, 256, 0, stream>>>(hbB, bna, bnb, Wd, bd, out, N);
}